// Round 8
// baseline (277.815 us; speedup 1.0000x reference)
//
#include <hip/hip_runtime.h>
#include <cstdint>

// MHA fused: qh = (q@Wq^T)*0.125*log2e, kh = k@Wk^T (+khT transposed copy),
// flash-causal-attn(qh,kh,V=kh) with deferred-normalization softmax, out = ao@Wo^T.
// B=4 T=2048 E=1024 H=16 D=64. v input (d_in[2]) DEAD (share_kv=True).
//
// flash_attn v8: exact v2 geometry (the measured optimum: 1024 blocks x 256
// threads, 4 waves x 32 q-rows sharing 32KB dbuf LDS -> 8KB LDS/wave,
// 16-wave/CU ceiling, 56us) + two verified VALU cuts from v3/v7:
//   - l-sum via ones-B-frag MFMA (no VALU adds, no epilogue shuffles)
//   - wave-uniform skip of fully-masked kt-iters (barrier still reached)
// Swapped QK^T + in-register P transpose (v2-verified).

typedef unsigned short u16;
typedef __attribute__((ext_vector_type(8))) short short8;
typedef __attribute__((ext_vector_type(4))) float f32x4;
typedef __attribute__((ext_vector_type(4))) unsigned short u16x4;
typedef __attribute__((ext_vector_type(2))) unsigned int u32x2;

__device__ __forceinline__ u16 f2bf(float x) {
  unsigned int u = __float_as_uint(x);
  u += 0x7fffu + ((u >> 16) & 1u);   // RNE
  return (u16)(u >> 16);
}

__device__ __forceinline__ float fexp2(float x) {
#if __has_builtin(__builtin_amdgcn_exp2f)
  return __builtin_amdgcn_exp2f(x);
#else
  return __expf(x * 0.69314718056f);
#endif
}

__device__ __forceinline__ float frcp(float x) {
#if __has_builtin(__builtin_amdgcn_rcpf)
  return __builtin_amdgcn_rcpf(x);
#else
  return 1.0f / x;
#endif
}

__device__ __forceinline__ void load16_to_lds(const void* g, void* lds_base_uniform) {
  // HW writes LDS at wave-uniform base + lane*16; g is per-lane.
  __builtin_amdgcn_global_load_lds(
      (const __attribute__((address_space(1))) void*)g,
      (__attribute__((address_space(3))) void*)lds_base_uniform,
      16, 0, 0);
}

// pack two f32 -> one dword of 2 truncated bf16 (lo = a, hi = b)
__device__ __forceinline__ unsigned pack_bf16(float a, float b) {
  return __builtin_amdgcn_perm(__float_as_uint(b), __float_as_uint(a), 0x07060302u);
}

// swap halves: {x,y} -> x' = {x.lo32lanes, y.lo32lanes}, y' = {x.hi, y.hi}
__device__ __forceinline__ void plane32_swap(unsigned &x, unsigned &y) {
#if __has_builtin(__builtin_amdgcn_permlane32_swap)
  u32x2 r = __builtin_amdgcn_permlane32_swap(x, y, false, false);
  x = r.x; y = r.y;
#else
  asm volatile("v_permlane32_swap_b32 %0, %1" : "+v"(x), "+v"(y));
#endif
}

__device__ __forceinline__ void plane16_swap(unsigned &x, unsigned &y) {
#if __has_builtin(__builtin_amdgcn_permlane16_swap)
  u32x2 r = __builtin_amdgcn_permlane16_swap(x, y, false, false);
  x = r.x; y = r.y;
#else
  asm volatile("v_permlane16_swap_b32 %0, %1" : "+v"(x), "+v"(y));
#endif
}

// ---------------- all casts, one dispatch ----------------
// float4-group index space: q[0,2097152) k[..4194304) Wq[..4456448)
// Wk[..4718592) Wo[..4980736). grid 19456 x 256.
__global__ void cast_all(const float* __restrict__ q, const float* __restrict__ k,
                         const float* __restrict__ Wq, const float* __restrict__ Wk,
                         const float* __restrict__ Wo,
                         u16* __restrict__ qb, u16* __restrict__ kb,
                         u16* __restrict__ Wqb, u16* __restrict__ Wkb,
                         u16* __restrict__ Wob) {
  int i = blockIdx.x * 256 + threadIdx.x;
  const float* s; u16* d; int off;
  if (i < 2097152)      { s = q;  d = qb;  off = i; }
  else if (i < 4194304) { s = k;  d = kb;  off = i - 2097152; }
  else if (i < 4456448) { s = Wq; d = Wqb; off = i - 4194304; }
  else if (i < 4718592) { s = Wk; d = Wkb; off = i - 4456448; }
  else                  { s = Wo; d = Wob; off = i - 4718592; }
  float4 f = ((const float4*)s)[off];
  uint2 p;
  p.x = (unsigned int)f2bf(f.x) | ((unsigned int)f2bf(f.y) << 16);
  p.y = (unsigned int)f2bf(f.z) | ((unsigned int)f2bf(f.w) << 16);
  ((uint2*)d)[off] = p;
}

// ---------------- GEMM mainloop: C128x128 = A(128xK) * W(128xK)^T ----------------
// BK=64, double-buffered LDS (2x16KB per operand). XOR-swizzled 16B chunks:
// phys chunk (row*8 + c8) holds logical cols ((c8 ^ (row&7))*8 ..+7).
// K = 1024 fixed. 4 waves, 2x2 wave grid, 4x4 16x16x32 frags per wave.
__device__ __forceinline__ void gemm_mainloop(
    const u16* __restrict__ A, const u16* __restrict__ W,
    u16* As, u16* Bs, int tm, int tn, int w, int lane, f32x4 acc[4][4])
{
  const int K = 1024;
  const int wr = (w >> 1) * 64, wc = (w & 1) * 64;
  const int l15 = lane & 15, l4 = lane >> 4;
  const int srow = lane >> 3;
  const int scol = ((lane & 7) ^ ((lane >> 3) & 7)) * 8;

#define STAGE(k0, bf)                                                              \
  {                                                                                \
    _Pragma("unroll")                                                              \
    for (int c = 0; c < 4; ++c) {                                                  \
      int j = w * 4 + c;                                                           \
      int row = j * 8 + srow;                                                      \
      load16_to_lds(A + (size_t)(tm + row) * K + (k0) + scol,                      \
                    (char*)(As + (bf) * 8192) + j * 1024);                         \
      load16_to_lds(W + (size_t)(tn + row) * K + (k0) + scol,                      \
                    (char*)(Bs + (bf) * 8192) + j * 1024);                         \
    }                                                                              \
  }

  STAGE(0, 0);
  __syncthreads();
  for (int t = 0; t < 16; ++t) {
    if (t < 15) STAGE((t + 1) << 6, (t + 1) & 1);
    const u16* Ac = As + (t & 1) * 8192;
    const u16* Bc = Bs + (t & 1) * 8192;
#pragma unroll
    for (int kc = 0; kc < 2; ++kc) {
      short8 af[4], bfr[4];
#pragma unroll
      for (int tt = 0; tt < 4; ++tt) {
        int ra = wr + tt * 16 + l15, rb = wc + tt * 16 + l15;
        af[tt]  = *(const short8*)&Ac[ra * 64 + (((kc * 4 + l4) ^ (ra & 7)) * 8)];
        bfr[tt] = *(const short8*)&Bc[rb * 64 + (((kc * 4 + l4) ^ (rb & 7)) * 8)];
      }
#pragma unroll
      for (int rt = 0; rt < 4; ++rt)
#pragma unroll
        for (int nt = 0; nt < 4; ++nt)
          acc[rt][nt] = __builtin_amdgcn_mfma_f32_16x16x32_bf16(af[rt], bfr[nt], acc[rt][nt], 0, 0, 0);
    }
    __syncthreads();   // drains: frag ds_reads (all waves) + next buffer's DMA
  }
#undef STAGE
}

// ---------------- Q + K projections, one dispatch (grid.z selects) ----------------
__global__ __launch_bounds__(256) void gemm_qk(
    const u16* __restrict__ qb, const u16* __restrict__ Wq,
    const u16* __restrict__ kb, const u16* __restrict__ Wk,
    u16* __restrict__ qh, u16* __restrict__ kh, u16* __restrict__ khT)
{
  __shared__ __align__(16) u16 As[2 * 8192];
  __shared__ __align__(16) u16 Bs[2 * 8192];
  const int z = blockIdx.z;
  const u16* A = z ? kb : qb;
  const u16* W = z ? Wk : Wq;
  const int tid = threadIdx.x, w = tid >> 6, lane = tid & 63;
  const int l15 = lane & 15, l4 = lane >> 4;
  const int tm = blockIdx.y * 128, tn = blockIdx.x * 128;
  const int wr = (w >> 1) * 64, wc = (w & 1) * 64;
  const int N = 1024;

  f32x4 zero4 = {0.f, 0.f, 0.f, 0.f};
  f32x4 acc[4][4];
  for (int i = 0; i < 4; ++i)
    for (int j = 0; j < 4; ++j) acc[i][j] = zero4;

  gemm_mainloop(A, W, As, Bs, tm, tn, w, lane, acc);

  const float scale = z ? 1.0f : 0.18033688011112042f;   // Q: 0.125*log2(e)
  u16* C = z ? kh : qh;
#pragma unroll
  for (int rt = 0; rt < 4; ++rt)
#pragma unroll
    for (int nt = 0; nt < 4; ++nt) {
      int row0 = tm + wr + rt * 16 + l4 * 4;
      int col = tn + wc + nt * 16 + l15;
      u16 vb[4];
#pragma unroll
      for (int r = 0; r < 4; ++r) vb[r] = f2bf(acc[rt][nt][r] * scale);
#pragma unroll
      for (int r = 0; r < 4; ++r)
        C[(size_t)(row0 + r) * N + col] = vb[r];
      if (z) {
        int b = row0 >> 11, t = row0 & 2047;
        int h = col >> 6, d = col & 63;
        u16x4 pack = {vb[0], vb[1], vb[2], vb[3]};
        *(u16x4*)&khT[(((size_t)(b * 16 + h) * 64 + d) << 11) + t] = pack;
      }
    }
}

// ---------------- O projection, f32 out ----------------
__global__ __launch_bounds__(256) void gemm_o(
    const u16* __restrict__ A, const u16* __restrict__ W, float* __restrict__ out)
{
  __shared__ __align__(16) u16 As[2 * 8192];
  __shared__ __align__(16) u16 Bs[2 * 8192];
  const int tid = threadIdx.x, w = tid >> 6, lane = tid & 63;
  const int l15 = lane & 15, l4 = lane >> 4;
  const int tm = blockIdx.y * 128, tn = blockIdx.x * 128;
  const int wr = (w >> 1) * 64, wc = (w & 1) * 64;
  const int N = 1024;

  f32x4 zero4 = {0.f, 0.f, 0.f, 0.f};
  f32x4 acc[4][4];
  for (int i = 0; i < 4; ++i)
    for (int j = 0; j < 4; ++j) acc[i][j] = zero4;

  gemm_mainloop(A, W, As, Bs, tm, tn, w, lane, acc);

#pragma unroll
  for (int rt = 0; rt < 4; ++rt)
#pragma unroll
    for (int nt = 0; nt < 4; ++nt) {
      int row0 = tm + wr + rt * 16 + l4 * 4;
      int col = tn + wc + nt * 16 + l15;
#pragma unroll
      for (int r = 0; r < 4; ++r)
        out[(size_t)(row0 + r) * N + col] = acc[rt][nt][r];
    }
}

// ---------------- causal flash attention, V = K, deferred-norm ----------------
// grid 1024: one 128-row Q-tile per block (big tiles first, XCD-swizzled),
// 256 threads = 4 waves x 32 q-rows (8KB LDS/wave -> 16-wave/CU ceiling).
// Swapped QK^T; P->A-frag via in-register transpose; l-sum via ones-B-frag
// MFMA; fully-masked kt-iters skipped wave-uniformly (barrier still reached).
__global__ __launch_bounds__(256, 4) void flash_attn(
    const u16* __restrict__ qh, const u16* __restrict__ kh,
    const u16* __restrict__ khT, u16* __restrict__ ao)
{
  const int T = 2048, E = 1024;
  __shared__ __align__(16) u16 Ks[2 * 4096];     // [buf][keys x d] swizzled
  __shared__ __align__(16) u16 Kt[2 * 4096];     // [buf][d x keys] swizzled

  const int L = blockIdx.x;                      // 0..1023
  const int xcd = L & 7;
  const int li = L >> 3;                         // 0..127
  const int tile = 15 - (li >> 3);               // 128-row Q-tile, big first
  const int bh = xcd * 8 + (li & 7);             // 8 bh per XCD (L2 pinning)
  const int b = bh >> 4, h = bh & 15;
  const size_t base = (size_t)b * T * E + (size_t)h * 64;
  const size_t tb = (size_t)bh * 64 * 2048;
  const int tid = threadIdx.x, w = tid >> 6, lane = tid & 63;
  const int l15 = lane & 15, l4 = lane >> 4;
  const int sw8 = (l4 ^ (l15 & 7)) * 8;          // swizzled in-row offset, kc=0
  f32x4 zero4 = {0.f, 0.f, 0.f, 0.f};
  const short ob = (short)0x3F80;                // bf16 1.0
  const short8 ones8 = {ob, ob, ob, ob, ob, ob, ob, ob};

  // 4 waves stage 16KB: wave w covers 1KB chunks ch = w*2, w*2+1 of each buf
#define STAGEK(kt, bf)                                                             \
  {                                                                                \
    int kbase_ = (kt) * 64;                                                        \
    _Pragma("unroll")                                                              \
    for (int c = 0; c < 2; ++c) {                                                  \
      int ch = (w * 2 + c) * 64 + lane;                                            \
      int row = ch >> 3;                                                           \
      int col = ((ch & 7) ^ (row & 7)) * 8;                                        \
      load16_to_lds(kh + base + (size_t)(kbase_ + row) * E + col,                  \
                    (char*)(Ks + (bf) * 4096) + (w * 2 + c) * 1024);               \
      load16_to_lds(khT + tb + (size_t)row * 2048 + kbase_ + col,                  \
                    (char*)(Kt + (bf) * 4096) + (w * 2 + c) * 1024);               \
    }                                                                              \
  }

  const int qbase = tile * 128;
  const int wq = qbase + w * 32;                 // wave's first q-row

  short8 qf[2][2];
#pragma unroll
  for (int mt = 0; mt < 2; ++mt)
#pragma unroll
    for (int kc = 0; kc < 2; ++kc)
      qf[mt][kc] = *(const short8*)&qh[base + (size_t)(wq + mt * 16 + l15) * E + kc * 32 + l4 * 8];

  f32x4 o[2][4];
  f32x4 ol[2];
#pragma unroll
  for (int mt = 0; mt < 2; ++mt) {
    ol[mt] = zero4;
#pragma unroll
    for (int dt = 0; dt < 4; ++dt) o[mt][dt] = zero4;
  }

  const int nkt = tile * 2 + 2;
  STAGEK(0, 0);
  __syncthreads();
  for (int kt = 0; kt < nkt; ++kt) {
    const int kbase = kt * 64;
    if (kt + 1 < nkt) STAGEK(kt + 1, (kt + 1) & 1);
    const u16* KsC = Ks + (kt & 1) * 4096;
    const u16* KtC = Kt + (kt & 1) * 4096;

    if (kbase <= wq + 31) {                      // wave-uniform: skip fully-masked iters
      // S^T = K Q^T : lane holds S[key = kbase+nt*16+l4*4+r][q = wq+mt*16+l15]
      f32x4 s[4][2];
#pragma unroll
      for (int nt = 0; nt < 4; ++nt) {
        s[nt][0] = zero4; s[nt][1] = zero4;
#pragma unroll
        for (int kc = 0; kc < 2; ++kc) {
          short8 kf = *(const short8*)&KsC[(nt * 16 + l15) * 64 + (sw8 ^ (kc * 32))];
          s[nt][0] = __builtin_amdgcn_mfma_f32_16x16x32_bf16(kf, qf[0][kc], s[nt][0], 0, 0, 0);
          s[nt][1] = __builtin_amdgcn_mfma_f32_16x16x32_bf16(kf, qf[1][kc], s[nt][1], 0, 0, 0);
        }
      }

      // p = 2^s (deferred norm), mask, pack to bf16, in-register transpose
      // to PV A-frags: dest lane l4' holds keys kc*32 + l4'*8..+7 for q = l15.
      short8 pf[2][2];
#pragma unroll
      for (int mt = 0; mt < 2; ++mt) {
        unsigned pk[4][2];                        // [nt][dword-pair], keys l4*4+{01,23}
        const int qrow = wq + mt * 16 + l15;
        if (kbase + 63 > wq + mt * 16) {          // wave-uniform per mt
#pragma unroll
          for (int nt = 0; nt < 4; ++nt) {
            const int kk = kbase + nt * 16 + l4 * 4;
            float p0 = fexp2(s[nt][mt][0]); p0 = (kk + 0 > qrow) ? 0.f : p0;
            float p1 = fexp2(s[nt][mt][1]); p1 = (kk + 1 > qrow) ? 0.f : p1;
            float p2 = fexp2(s[nt][mt][2]); p2 = (kk + 2 > qrow) ? 0.f : p2;
            float p3 = fexp2(s[nt][mt][3]); p3 = (kk + 3 > qrow) ? 0.f : p3;
            pk[nt][0] = pack_bf16(p0, p1);
            pk[nt][1] = pack_bf16(p2, p3);
          }
        } else {
#pragma unroll
          for (int nt = 0; nt < 4; ++nt) {
            pk[nt][0] = pack_bf16(fexp2(s[nt][mt][0]), fexp2(s[nt][mt][1]));
            pk[nt][1] = pack_bf16(fexp2(s[nt][mt][2]), fexp2(s[nt][mt][3]));
          }
        }
        // 4x4 dword transpose (lane-group l4 <-> register index)
#pragma unroll
        for (int kc = 0; kc < 2; ++kc) {
          unsigned X0 = pk[2 * kc][0], X1 = pk[2 * kc][1];
          unsigned Y0 = pk[2 * kc + 1][0], Y1 = pk[2 * kc + 1][1];
          plane32_swap(X0, Y0);
          plane32_swap(X1, Y1);
          plane16_swap(X0, Y0);
          plane16_swap(X1, Y1);
          union { unsigned uu[4]; short8 s8; } cvt;
          cvt.uu[0] = X0; cvt.uu[1] = X1; cvt.uu[2] = Y0; cvt.uu[3] = Y1;
          pf[mt][kc] = cvt.s8;
        }
      }

      // O += P * V  (V = K); l += P * ones (row-sum at q=l4*4+r, dup over l15)
#pragma unroll
      for (int kc = 0; kc < 2; ++kc) {
#pragma unroll
        for (int dt = 0; dt < 4; ++dt) {
          short8 vfr = *(const short8*)&KtC[(dt * 16 + l15) * 64 + (sw8 ^ (kc * 32))];
          o[0][dt] = __builtin_amdgcn_mfma_f32_16x16x32_bf16(pf[0][kc], vfr, o[0][dt], 0, 0, 0);
          o[1][dt] = __builtin_amdgcn_mfma_f32_16x16x32_bf16(pf[1][kc], vfr, o[1][dt], 0, 0, 0);
        }
        ol[0] = __builtin_amdgcn_mfma_f32_16x16x32_bf16(pf[0][kc], ones8, ol[0], 0, 0, 0);
        ol[1] = __builtin_amdgcn_mfma_f32_16x16x32_bf16(pf[1][kc], ones8, ol[1], 0, 0, 0);
      }
    }
    __syncthreads();   // publishes next buffer; protects current buffer reads
  }

  // normalize + store (ol[mt][r] = row-sum for q = wq+mt*16+l4*4+r, no shuffles)
#pragma unroll
  for (int mt = 0; mt < 2; ++mt) {
    float inv[4];
#pragma unroll
    for (int r = 0; r < 4; ++r) inv[r] = frcp(ol[mt][r]);
#pragma unroll
    for (int dt = 0; dt < 4; ++dt)
#pragma unroll
      for (int r = 0; r < 4; ++r) {
        int row = wq + mt * 16 + l4 * 4 + r;
        ao[base + (size_t)row * E + dt * 16 + l15] = f2bf(o[mt][dt][r] * inv[r]);
      }
  }
#undef STAGEK
}

extern "C" void kernel_launch(void* const* d_in, const int* in_sizes, int n_in,
                              void* d_out, int out_size, void* d_ws, size_t ws_size,
                              hipStream_t stream) {
  (void)in_sizes; (void)n_in; (void)out_size; (void)ws_size;
  const float* q  = (const float*)d_in[0];
  const float* k  = (const float*)d_in[1];
  // d_in[2] = v : unused (share_kv=True)
  const float* Wq = (const float*)d_in[3];
  const float* Wk = (const float*)d_in[4];
  const float* Wo = (const float*)d_in[5];
  float* out = (float*)d_out;

  const size_t nBTE = (size_t)4 * 2048 * 1024;   // 8388608
  const size_t nEE  = (size_t)1024 * 1024;

  char* p = (char*)d_ws;
  u16* q_b  = (u16*)p; p += nBTE * 2;
  u16* k_b  = (u16*)p; p += nBTE * 2;
  u16* Wq_b = (u16*)p; p += nEE * 2;
  u16* Wk_b = (u16*)p; p += nEE * 2;
  u16* Wo_b = (u16*)p; p += nEE * 2;
  u16* qh   = (u16*)p; p += nBTE * 2;
  u16* kh   = (u16*)p; p += nBTE * 2;
  u16* khT  = (u16*)p; p += nBTE * 2;
  u16* ao   = q_b;   // alias: q_b dead after Q-GEMM; flash writes ao after that

  cast_all<<<dim3(19456), 256, 0, stream>>>(q, k, Wq, Wk, Wo,
                                            q_b, k_b, Wq_b, Wk_b, Wo_b);

  gemm_qk<<<dim3(8, 64, 2), 256, 0, stream>>>(q_b, Wq_b, k_b, Wk_b, qh, kh, khT);

  flash_attn<<<dim3(1024), 256, 0, stream>>>(qh, kh, khT, ao);

  gemm_o<<<dim3(8, 64), 256, 0, stream>>>(ao, Wo_b, out);
}

// Round 9
// 255.102 us; speedup vs baseline: 1.0890x; 1.0890x over previous
//
#include <hip/hip_runtime.h>
#include <cstdint>

// MHA fused: qh = (q@Wq^T)*0.125*log2e, kh = k@Wk^T (+khT transposed copy),
// flash-causal-attn(qh,kh,V=kh) with deferred-normalization softmax, out = ao@Wo^T.
// B=4 T=2048 E=1024 H=16 D=64. v input (d_in[2]) DEAD (share_kv=True).
//
// flash_attn: EXACT round-2 v2 (measured 56us optimum: 1024 blocks x 256 thr,
// 4 waves x 32 q-rows, 32KB dbuf LDS, swapped QK^T, in-reg P transpose,
// VALU l-sum + epilogue shuffles, branch-free body). v8's grafts (ones-MFMA
// l-sum, skip-branch) REGRESSED 56->74 (skip-if killed cross-iter pipelining);
// reverted.
// gemm_qk/gemm_o: + XCD-contiguous block swizzle (T1): blocks sharing an
// A-panel land on one XCD's L2 (swz = (bid%8)*64 + bid/8, bijective).

typedef unsigned short u16;
typedef __attribute__((ext_vector_type(8))) short short8;
typedef __attribute__((ext_vector_type(4))) float f32x4;
typedef __attribute__((ext_vector_type(4))) unsigned short u16x4;
typedef __attribute__((ext_vector_type(2))) unsigned int u32x2;

__device__ __forceinline__ u16 f2bf(float x) {
  unsigned int u = __float_as_uint(x);
  u += 0x7fffu + ((u >> 16) & 1u);   // RNE
  return (u16)(u >> 16);
}

__device__ __forceinline__ float fexp2(float x) {
#if __has_builtin(__builtin_amdgcn_exp2f)
  return __builtin_amdgcn_exp2f(x);
#else
  return __expf(x * 0.69314718056f);
#endif
}

__device__ __forceinline__ float frcp(float x) {
#if __has_builtin(__builtin_amdgcn_rcpf)
  return __builtin_amdgcn_rcpf(x);
#else
  return 1.0f / x;
#endif
}

__device__ __forceinline__ void load16_to_lds(const void* g, void* lds_base_uniform) {
  // HW writes LDS at wave-uniform base + lane*16; g is per-lane.
  __builtin_amdgcn_global_load_lds(
      (const __attribute__((address_space(1))) void*)g,
      (__attribute__((address_space(3))) void*)lds_base_uniform,
      16, 0, 0);
}

// pack two f32 -> one dword of 2 truncated bf16 (lo = a, hi = b)
__device__ __forceinline__ unsigned pack_bf16(float a, float b) {
  return __builtin_amdgcn_perm(__float_as_uint(b), __float_as_uint(a), 0x07060302u);
}

// swap halves: {x,y} -> x' = {x.lo32lanes, y.lo32lanes}, y' = {x.hi, y.hi}
__device__ __forceinline__ void plane32_swap(unsigned &x, unsigned &y) {
#if __has_builtin(__builtin_amdgcn_permlane32_swap)
  u32x2 r = __builtin_amdgcn_permlane32_swap(x, y, false, false);
  x = r.x; y = r.y;
#else
  asm volatile("v_permlane32_swap_b32 %0, %1" : "+v"(x), "+v"(y));
#endif
}

__device__ __forceinline__ void plane16_swap(unsigned &x, unsigned &y) {
#if __has_builtin(__builtin_amdgcn_permlane16_swap)
  u32x2 r = __builtin_amdgcn_permlane16_swap(x, y, false, false);
  x = r.x; y = r.y;
#else
  asm volatile("v_permlane16_swap_b32 %0, %1" : "+v"(x), "+v"(y));
#endif
}

// ---------------- all casts, one dispatch ----------------
// float4-group index space: q[0,2097152) k[..4194304) Wq[..4456448)
// Wk[..4718592) Wo[..4980736). grid 19456 x 256.
__global__ void cast_all(const float* __restrict__ q, const float* __restrict__ k,
                         const float* __restrict__ Wq, const float* __restrict__ Wk,
                         const float* __restrict__ Wo,
                         u16* __restrict__ qb, u16* __restrict__ kb,
                         u16* __restrict__ Wqb, u16* __restrict__ Wkb,
                         u16* __restrict__ Wob) {
  int i = blockIdx.x * 256 + threadIdx.x;
  const float* s; u16* d; int off;
  if (i < 2097152)      { s = q;  d = qb;  off = i; }
  else if (i < 4194304) { s = k;  d = kb;  off = i - 2097152; }
  else if (i < 4456448) { s = Wq; d = Wqb; off = i - 4194304; }
  else if (i < 4718592) { s = Wk; d = Wkb; off = i - 4456448; }
  else                  { s = Wo; d = Wob; off = i - 4718592; }
  float4 f = ((const float4*)s)[off];
  uint2 p;
  p.x = (unsigned int)f2bf(f.x) | ((unsigned int)f2bf(f.y) << 16);
  p.y = (unsigned int)f2bf(f.z) | ((unsigned int)f2bf(f.w) << 16);
  ((uint2*)d)[off] = p;
}

// ---------------- GEMM mainloop: C128x128 = A(128xK) * W(128xK)^T ----------------
// BK=64, double-buffered LDS (2x16KB per operand). XOR-swizzled 16B chunks:
// phys chunk (row*8 + c8) holds logical cols ((c8 ^ (row&7))*8 ..+7).
// K = 1024 fixed. 4 waves, 2x2 wave grid, 4x4 16x16x32 frags per wave.
__device__ __forceinline__ void gemm_mainloop(
    const u16* __restrict__ A, const u16* __restrict__ W,
    u16* As, u16* Bs, int tm, int tn, int w, int lane, f32x4 acc[4][4])
{
  const int K = 1024;
  const int wr = (w >> 1) * 64, wc = (w & 1) * 64;
  const int l15 = lane & 15, l4 = lane >> 4;
  const int srow = lane >> 3;
  const int scol = ((lane & 7) ^ ((lane >> 3) & 7)) * 8;

#define STAGE(k0, bf)                                                              \
  {                                                                                \
    _Pragma("unroll")                                                              \
    for (int c = 0; c < 4; ++c) {                                                  \
      int j = w * 4 + c;                                                           \
      int row = j * 8 + srow;                                                      \
      load16_to_lds(A + (size_t)(tm + row) * K + (k0) + scol,                      \
                    (char*)(As + (bf) * 8192) + j * 1024);                         \
      load16_to_lds(W + (size_t)(tn + row) * K + (k0) + scol,                      \
                    (char*)(Bs + (bf) * 8192) + j * 1024);                         \
    }                                                                              \
  }

  STAGE(0, 0);
  __syncthreads();
  for (int t = 0; t < 16; ++t) {
    if (t < 15) STAGE((t + 1) << 6, (t + 1) & 1);
    const u16* Ac = As + (t & 1) * 8192;
    const u16* Bc = Bs + (t & 1) * 8192;
#pragma unroll
    for (int kc = 0; kc < 2; ++kc) {
      short8 af[4], bfr[4];
#pragma unroll
      for (int tt = 0; tt < 4; ++tt) {
        int ra = wr + tt * 16 + l15, rb = wc + tt * 16 + l15;
        af[tt]  = *(const short8*)&Ac[ra * 64 + (((kc * 4 + l4) ^ (ra & 7)) * 8)];
        bfr[tt] = *(const short8*)&Bc[rb * 64 + (((kc * 4 + l4) ^ (rb & 7)) * 8)];
      }
#pragma unroll
      for (int rt = 0; rt < 4; ++rt)
#pragma unroll
        for (int nt = 0; nt < 4; ++nt)
          acc[rt][nt] = __builtin_amdgcn_mfma_f32_16x16x32_bf16(af[rt], bfr[nt], acc[rt][nt], 0, 0, 0);
    }
    __syncthreads();   // drains: frag ds_reads (all waves) + next buffer's DMA
  }
#undef STAGE
}

// ---------------- Q + K projections, one dispatch (grid.z selects) ----------------
// Block swizzle: lin = x + 8*y (0..511 per z); swz = (lin%8)*64 + lin/8 so each
// XCD's 64 blocks cover 8 consecutive A-panels completely (A-panel L2 reuse).
__global__ __launch_bounds__(256) void gemm_qk(
    const u16* __restrict__ qb, const u16* __restrict__ Wq,
    const u16* __restrict__ kb, const u16* __restrict__ Wk,
    u16* __restrict__ qh, u16* __restrict__ kh, u16* __restrict__ khT)
{
  __shared__ __align__(16) u16 As[2 * 8192];
  __shared__ __align__(16) u16 Bs[2 * 8192];
  const int z = blockIdx.z;
  const u16* A = z ? kb : qb;
  const u16* W = z ? Wk : Wq;
  const int tid = threadIdx.x, w = tid >> 6, lane = tid & 63;
  const int l15 = lane & 15, l4 = lane >> 4;
  const int lin = blockIdx.x + 8 * blockIdx.y;   // 0..511
  const int swz = (lin & 7) * 64 + (lin >> 3);   // XCD-contiguous remap
  const int tm = (swz >> 3) * 128, tn = (swz & 7) * 128;
  const int wr = (w >> 1) * 64, wc = (w & 1) * 64;
  const int N = 1024;

  f32x4 zero4 = {0.f, 0.f, 0.f, 0.f};
  f32x4 acc[4][4];
  for (int i = 0; i < 4; ++i)
    for (int j = 0; j < 4; ++j) acc[i][j] = zero4;

  gemm_mainloop(A, W, As, Bs, tm, tn, w, lane, acc);

  const float scale = z ? 1.0f : 0.18033688011112042f;   // Q: 0.125*log2(e)
  u16* C = z ? kh : qh;
#pragma unroll
  for (int rt = 0; rt < 4; ++rt)
#pragma unroll
    for (int nt = 0; nt < 4; ++nt) {
      int row0 = tm + wr + rt * 16 + l4 * 4;
      int col = tn + wc + nt * 16 + l15;
      u16 vb[4];
#pragma unroll
      for (int r = 0; r < 4; ++r) vb[r] = f2bf(acc[rt][nt][r] * scale);
#pragma unroll
      for (int r = 0; r < 4; ++r)
        C[(size_t)(row0 + r) * N + col] = vb[r];
      if (z) {
        int b = row0 >> 11, t = row0 & 2047;
        int h = col >> 6, d = col & 63;
        u16x4 pack = {vb[0], vb[1], vb[2], vb[3]};
        *(u16x4*)&khT[(((size_t)(b * 16 + h) * 64 + d) << 11) + t] = pack;
      }
    }
}

// ---------------- O projection, f32 out ----------------
__global__ __launch_bounds__(256) void gemm_o(
    const u16* __restrict__ A, const u16* __restrict__ W, float* __restrict__ out)
{
  __shared__ __align__(16) u16 As[2 * 8192];
  __shared__ __align__(16) u16 Bs[2 * 8192];
  const int tid = threadIdx.x, w = tid >> 6, lane = tid & 63;
  const int l15 = lane & 15, l4 = lane >> 4;
  const int lin = blockIdx.x + 8 * blockIdx.y;   // 0..511
  const int swz = (lin & 7) * 64 + (lin >> 3);   // XCD-contiguous remap
  const int tm = (swz >> 3) * 128, tn = (swz & 7) * 128;
  const int wr = (w >> 1) * 64, wc = (w & 1) * 64;
  const int N = 1024;

  f32x4 zero4 = {0.f, 0.f, 0.f, 0.f};
  f32x4 acc[4][4];
  for (int i = 0; i < 4; ++i)
    for (int j = 0; j < 4; ++j) acc[i][j] = zero4;

  gemm_mainloop(A, W, As, Bs, tm, tn, w, lane, acc);

#pragma unroll
  for (int rt = 0; rt < 4; ++rt)
#pragma unroll
    for (int nt = 0; nt < 4; ++nt) {
      int row0 = tm + wr + rt * 16 + l4 * 4;
      int col = tn + wc + nt * 16 + l15;
#pragma unroll
      for (int r = 0; r < 4; ++r)
        out[(size_t)(row0 + r) * N + col] = acc[rt][nt][r];
    }
}

// ---------------- causal flash attention, V = K, deferred-norm ----------------
// EXACT round-2 v2: grid 1024 (one 128-row Q-tile per block, big tiles first,
// XCD-swizzled), 4 waves x 32 q-rows, Ks/Kt double-buffered (2x8KB each),
// ONE barrier per iter. Swapped QK^T; P packed (v_perm) + permlane-transposed
// to PV A-frags in-register; VALU l-sum + epilogue shuffles; branch-free body.
__global__ __launch_bounds__(256, 4) void flash_attn(
    const u16* __restrict__ qh, const u16* __restrict__ kh,
    const u16* __restrict__ khT, u16* __restrict__ ao)
{
  const int T = 2048, E = 1024;
  __shared__ __align__(16) u16 Ks[2 * 4096];     // [buf][keys x d] swizzled
  __shared__ __align__(16) u16 Kt[2 * 4096];     // [buf][d x keys] swizzled

  const int L = blockIdx.x;                      // 0..1023
  const int xcd = L & 7;
  const int li = L >> 3;                         // 0..127
  const int tile = 15 - (li >> 3);               // big tiles first
  const int bh = xcd * 8 + (li & 7);             // 8 bh per XCD
  const int b = bh >> 4, h = bh & 15;
  const size_t base = (size_t)b * T * E + (size_t)h * 64;
  const size_t tb = (size_t)bh * 64 * 2048;
  const int tid = threadIdx.x, w = tid >> 6, lane = tid & 63;
  const int l15 = lane & 15, l4 = lane >> 4;
  const int sw8 = (l4 ^ (l15 & 7)) * 8;          // swizzled in-row offset, kc=0
  f32x4 zero4 = {0.f, 0.f, 0.f, 0.f};

#define STAGEK(kt, bf)                                                             \
  {                                                                                \
    int kbase_ = (kt) * 64;                                                        \
    _Pragma("unroll")                                                              \
    for (int c = 0; c < 2; ++c) {                                                  \
      int ch = (w * 2 + c) * 64 + lane;                                            \
      int row = ch >> 3;                                                           \
      int col = ((ch & 7) ^ (row & 7)) * 8;                                        \
      load16_to_lds(kh + base + (size_t)(kbase_ + row) * E + col,                  \
                    (char*)(Ks + (bf) * 4096) + (w * 2 + c) * 1024);               \
      load16_to_lds(khT + tb + (size_t)row * 2048 + kbase_ + col,                  \
                    (char*)(Kt + (bf) * 4096) + (w * 2 + c) * 1024);               \
    }                                                                              \
  }

  const int qbase = tile * 128;
  const int wq = qbase + w * 32;

  short8 qf[2][2];
#pragma unroll
  for (int mt = 0; mt < 2; ++mt)
#pragma unroll
    for (int kc = 0; kc < 2; ++kc)
      qf[mt][kc] = *(const short8*)&qh[base + (size_t)(wq + mt * 16 + l15) * E + kc * 32 + l4 * 8];

  f32x4 o[2][4];
  float l_i[2] = {0.f, 0.f};
#pragma unroll
  for (int mt = 0; mt < 2; ++mt)
#pragma unroll
    for (int dt = 0; dt < 4; ++dt) o[mt][dt] = zero4;

  const int nkt = tile * 2 + 2;
  STAGEK(0, 0);
  __syncthreads();
  for (int kt = 0; kt < nkt; ++kt) {
    const int kbase = kt * 64;
    if (kt + 1 < nkt) STAGEK(kt + 1, (kt + 1) & 1);
    const u16* KsC = Ks + (kt & 1) * 4096;
    const u16* KtC = Kt + (kt & 1) * 4096;

    // S^T = K Q^T : lane holds S[key = kbase+nt*16+l4*4+r][q = wq+mt*16+l15]
    f32x4 s[4][2];
#pragma unroll
    for (int nt = 0; nt < 4; ++nt) {
      s[nt][0] = zero4; s[nt][1] = zero4;
#pragma unroll
      for (int kc = 0; kc < 2; ++kc) {
        short8 kf = *(const short8*)&KsC[(nt * 16 + l15) * 64 + (sw8 ^ (kc * 32))];
        s[nt][0] = __builtin_amdgcn_mfma_f32_16x16x32_bf16(kf, qf[0][kc], s[nt][0], 0, 0, 0);
        s[nt][1] = __builtin_amdgcn_mfma_f32_16x16x32_bf16(kf, qf[1][kc], s[nt][1], 0, 0, 0);
      }
    }

    // p = 2^s (deferred norm), mask, pack to bf16, in-register transpose
    // to PV A-frags: dest lane l4' holds keys kc*32 + l4'*8..+7 for q = l15.
    short8 pf[2][2];
#pragma unroll
    for (int mt = 0; mt < 2; ++mt) {
      unsigned pk[4][2];                          // [nt][dword-pair], keys l4*4+{01,23}
      float acc = 0.f;
      const int qrow = wq + mt * 16 + l15;
      if (kbase + 63 > wq + mt * 16) {            // wave-uniform per mt
#pragma unroll
        for (int nt = 0; nt < 4; ++nt) {
          const int kk = kbase + nt * 16 + l4 * 4;
          float p0 = fexp2(s[nt][mt][0]); p0 = (kk + 0 > qrow) ? 0.f : p0;
          float p1 = fexp2(s[nt][mt][1]); p1 = (kk + 1 > qrow) ? 0.f : p1;
          float p2 = fexp2(s[nt][mt][2]); p2 = (kk + 2 > qrow) ? 0.f : p2;
          float p3 = fexp2(s[nt][mt][3]); p3 = (kk + 3 > qrow) ? 0.f : p3;
          acc += (p0 + p1) + (p2 + p3);
          pk[nt][0] = pack_bf16(p0, p1);
          pk[nt][1] = pack_bf16(p2, p3);
        }
      } else {
#pragma unroll
        for (int nt = 0; nt < 4; ++nt) {
          float p0 = fexp2(s[nt][mt][0]);
          float p1 = fexp2(s[nt][mt][1]);
          float p2 = fexp2(s[nt][mt][2]);
          float p3 = fexp2(s[nt][mt][3]);
          acc += (p0 + p1) + (p2 + p3);
          pk[nt][0] = pack_bf16(p0, p1);
          pk[nt][1] = pack_bf16(p2, p3);
        }
      }
      l_i[mt] += acc;
      // 4x4 dword transpose over (lane-group l4, register j):
      // swap32: reg-index <-> lane-bit5; swap16: reg-index <-> lane-bit4.
#pragma unroll
      for (int kc = 0; kc < 2; ++kc) {
        unsigned X0 = pk[2 * kc][0], X1 = pk[2 * kc][1];
        unsigned Y0 = pk[2 * kc + 1][0], Y1 = pk[2 * kc + 1][1];
        plane32_swap(X0, Y0);
        plane32_swap(X1, Y1);
        plane16_swap(X0, Y0);
        plane16_swap(X1, Y1);
        union { unsigned u[4]; short8 s8; } cvt;
        cvt.u[0] = X0; cvt.u[1] = X1; cvt.u[2] = Y0; cvt.u[3] = Y1;
        pf[mt][kc] = cvt.s8;
      }
    }

    // O += P * V  (V = K; B-frags from Kt rows, shared across m-frags)
#pragma unroll
    for (int kc = 0; kc < 2; ++kc) {
#pragma unroll
      for (int dt = 0; dt < 4; ++dt) {
        short8 vfr = *(const short8*)&KtC[(dt * 16 + l15) * 64 + (sw8 ^ (kc * 32))];
        o[0][dt] = __builtin_amdgcn_mfma_f32_16x16x32_bf16(pf[0][kc], vfr, o[0][dt], 0, 0, 0);
        o[1][dt] = __builtin_amdgcn_mfma_f32_16x16x32_bf16(pf[1][kc], vfr, o[1][dt], 0, 0, 0);
      }
    }
    __syncthreads();   // publishes next buffer; protects current buffer reads
  }

  // deferred l-reduction + normalize + store
#pragma unroll
  for (int mt = 0; mt < 2; ++mt) {
    float lt = l_i[mt];
    lt += __shfl_xor(lt, 16);
    lt += __shfl_xor(lt, 32);            // lt = full key-sum for q = wq+mt*16+l15
    float inv[4];
#pragma unroll
    for (int r = 0; r < 4; ++r) inv[r] = frcp(__shfl(lt, l4 * 4 + r));
#pragma unroll
    for (int dt = 0; dt < 4; ++dt)
#pragma unroll
      for (int r = 0; r < 4; ++r) {
        int row = wq + mt * 16 + l4 * 4 + r;
        ao[base + (size_t)row * E + dt * 16 + l15] = f2bf(o[mt][dt][r] * inv[r]);
      }
  }
#undef STAGEK
}

extern "C" void kernel_launch(void* const* d_in, const int* in_sizes, int n_in,
                              void* d_out, int out_size, void* d_ws, size_t ws_size,
                              hipStream_t stream) {
  (void)in_sizes; (void)n_in; (void)out_size; (void)ws_size;
  const float* q  = (const float*)d_in[0];
  const float* k  = (const float*)d_in[1];
  // d_in[2] = v : unused (share_kv=True)
  const float* Wq = (const float*)d_in[3];
  const float* Wk = (const float*)d_in[4];
  const float* Wo = (const float*)d_in[5];
  float* out = (float*)d_out;

  const size_t nBTE = (size_t)4 * 2048 * 1024;   // 8388608
  const size_t nEE  = (size_t)1024 * 1024;

  char* p = (char*)d_ws;
  u16* q_b  = (u16*)p; p += nBTE * 2;
  u16* k_b  = (u16*)p; p += nBTE * 2;
  u16* Wq_b = (u16*)p; p += nEE * 2;
  u16* Wk_b = (u16*)p; p += nEE * 2;
  u16* Wo_b = (u16*)p; p += nEE * 2;
  u16* qh   = (u16*)p; p += nBTE * 2;
  u16* kh   = (u16*)p; p += nBTE * 2;
  u16* khT  = (u16*)p; p += nBTE * 2;
  u16* ao   = q_b;   // alias: q_b dead after Q-GEMM; flash writes ao after that

  cast_all<<<dim3(19456), 256, 0, stream>>>(q, k, Wq, Wk, Wo,
                                            q_b, k_b, Wq_b, Wk_b, Wo_b);

  gemm_qk<<<dim3(8, 64, 2), 256, 0, stream>>>(q_b, Wq_b, k_b, Wk_b, qh, kh, khT);

  flash_attn<<<dim3(1024), 256, 0, stream>>>(qh, kh, khT, ao);

  gemm_o<<<dim3(8, 64), 256, 0, stream>>>(ao, Wo_b, out);
}